// Round 1
// baseline (318.963 us; speedup 1.0000x reference)
//
#include <hip/hip_runtime.h>

#define NB    4096
#define SEQ   64
#define DIM   128
#define NHEAD 8
#define ATTD  32
#define HKC   256
#define SCALE 0.17677669529663687f

typedef __bf16 bf16_t;
typedef __bf16 bf16x8 __attribute__((ext_vector_type(8)));
typedef __bf16 bf16x4 __attribute__((ext_vector_type(4)));
typedef float  f32x4  __attribute__((ext_vector_type(4)));

static __device__ __forceinline__ bf16_t f2bf(float f) {
  unsigned u = __builtin_bit_cast(unsigned, f);
  u = (u + 0x7FFFu + ((u >> 16) & 1u)) >> 16;
  unsigned short s = (unsigned short)u;
  return __builtin_bit_cast(bf16_t, s);
}

// ws layout (bf16): [0:32768) WqT[c][d], [32768:65536) WkT[c][d],
// [65536:98304) WvT[c][d], [98304:131072) WresT[c][d]
// where c = h*32+a (or res output col), d = 0..127. 16B-contiguous in d.
__global__ void prep_weights(const float* __restrict__ Wq,
                             const float* __restrict__ Wk,
                             const float* __restrict__ Wv,
                             const float* __restrict__ Wr,
                             bf16_t* __restrict__ ws) {
  int idx = blockIdx.x * 256 + threadIdx.x;  // 0..131071
  int m = idx >> 15;
  int e = idx & 32767;
  int c = e >> 7;
  int d = e & 127;
  float v;
  if (m == 0)      v = Wq[((c >> 5) * DIM + d) * ATTD + (c & 31)];
  else if (m == 1) v = Wk[((c >> 5) * DIM + d) * ATTD + (c & 31)];
  else if (m == 2) v = Wv[((c >> 5) * DIM + d) * ATTD + (c & 31)];
  else             v = Wr[d * HKC + c];
  ws[idx] = f2bf(v);
}

// One block per batch. 4 waves; wave w owns output cols [64w, 64w+64) = heads {2w, 2w+1}.
// After the single __syncthreads (X staging), everything is wave-private.
__launch_bounds__(256, 1)
__global__ void fused_attn(const float* __restrict__ xg,
                           const bf16_t* __restrict__ ws,
                           float* __restrict__ outg) {
  __shared__ bf16_t Xb[64][136];     // X bf16, pad 8 -> row stride 272B (bank step 4)
  __shared__ bf16_t Qb[64][264];     // Q row-major [m][h*32+a]
  __shared__ bf16_t Kb[64][264];     // K row-major [m][h*32+a]
  __shared__ bf16_t Vt[256][72];     // V transposed [h*32+a][m]
  __shared__ bf16_t Pw[4][64][72];   // per-wave softmax(P) row-major [m][n]

  const int t  = threadIdx.x;
  const int w  = t >> 6;
  const int l  = t & 63;
  const int lo = l & 15;
  const int g  = l >> 4;
  const int b  = blockIdx.x;
  const int c0 = w * 64;

  { // stage X -> LDS (bf16)
    const float* xb = xg + (size_t)b * (SEQ * DIM);
#pragma unroll
    for (int i = 0; i < 8; ++i) {
      int idx = i * 1024 + t * 4;
      float4 v = *(const float4*)(xb + idx);
      bf16x4 p;
      p[0] = f2bf(v.x); p[1] = f2bf(v.y); p[2] = f2bf(v.z); p[3] = f2bf(v.w);
      *(bf16x4*)&Xb[idx >> 7][idx & 127] = p;
    }
  }
  __syncthreads();

  const bf16_t* wsq = ws;
  const bf16_t* wsk = ws + 32768;
  const bf16_t* wsv = ws + 65536;
  const bf16_t* wsr = ws + 98304;

  // ---- Q,K projections, swapped orientation: OUT^T = W^T * X^T ----
  // A-frag: WT rows (global, contiguous k). B-frag: Xb rows (contiguous k).
  // D tile: row-dim = weight col c (g*4+j), col-dim = seq m (lo).
  // Store transposed -> Qb/Kb row-major with packed b64 writes.
#pragma unroll
  for (int mat = 0; mat < 2; ++mat) {
    const bf16_t* wm = mat ? wsk : wsq;
    f32x4 acc[4][4];
#pragma unroll
    for (int i = 0; i < 4; ++i)
#pragma unroll
      for (int j = 0; j < 4; ++j) acc[i][j] = f32x4{0.f, 0.f, 0.f, 0.f};
#pragma unroll
    for (int kk = 0; kk < 4; ++kk) {
      bf16x8 af[4], bx[4];
#pragma unroll
      for (int ct = 0; ct < 4; ++ct)
        af[ct] = *(const bf16x8*)(wm + (c0 + ct * 16 + lo) * DIM + kk * 32 + g * 8);
#pragma unroll
      for (int mt = 0; mt < 4; ++mt)
        bx[mt] = *(const bf16x8*)&Xb[mt * 16 + lo][kk * 32 + g * 8];
#pragma unroll
      for (int ct = 0; ct < 4; ++ct)
#pragma unroll
        for (int mt = 0; mt < 4; ++mt)
          acc[ct][mt] = __builtin_amdgcn_mfma_f32_16x16x32_bf16(af[ct], bx[mt], acc[ct][mt], 0, 0, 0);
    }
#pragma unroll
    for (int ct = 0; ct < 4; ++ct)
#pragma unroll
      for (int mt = 0; mt < 4; ++mt) {
        bf16x4 p;
#pragma unroll
        for (int j = 0; j < 4; ++j) p[j] = f2bf(acc[ct][mt][j]);
        if (mat == 0) *(bf16x4*)&Qb[mt * 16 + lo][c0 + ct * 16 + g * 4] = p;
        else          *(bf16x4*)&Kb[mt * 16 + lo][c0 + ct * 16 + g * 4] = p;
      }
  }

  // ---- V projection, original orientation: V = X * Wv ----
  // D tile: row-dim = seq m (g*4+j), col-dim = weight col (lo).
  // Store transposed -> Vt[c][m] with packed b64 writes.
  {
    f32x4 acc[4][4];
#pragma unroll
    for (int i = 0; i < 4; ++i)
#pragma unroll
      for (int j = 0; j < 4; ++j) acc[i][j] = f32x4{0.f, 0.f, 0.f, 0.f};
#pragma unroll
    for (int kk = 0; kk < 4; ++kk) {
      bf16x8 af[4], bw[4];
#pragma unroll
      for (int mt = 0; mt < 4; ++mt)
        af[mt] = *(const bf16x8*)&Xb[mt * 16 + lo][kk * 32 + g * 8];
#pragma unroll
      for (int nt = 0; nt < 4; ++nt)
        bw[nt] = *(const bf16x8*)(wsv + (c0 + nt * 16 + lo) * DIM + kk * 32 + g * 8);
#pragma unroll
      for (int mt = 0; mt < 4; ++mt)
#pragma unroll
        for (int nt = 0; nt < 4; ++nt)
          acc[mt][nt] = __builtin_amdgcn_mfma_f32_16x16x32_bf16(af[mt], bw[nt], acc[mt][nt], 0, 0, 0);
    }
#pragma unroll
    for (int mt = 0; mt < 4; ++mt)
#pragma unroll
      for (int nt = 0; nt < 4; ++nt) {
        bf16x4 p;
#pragma unroll
        for (int j = 0; j < 4; ++j) p[j] = f2bf(acc[mt][nt][j]);
        *(bf16x4*)&Vt[c0 + nt * 16 + lo][mt * 16 + g * 4] = p;
      }
  }

  // ---- attention per head (wave-private) + residual, fused accumulator ----
  f32x4 ctxacc[4][4];  // [mt][ct]; rows mt*16+g*4+j, cols c0+ct*16+lo
#pragma unroll
  for (int i = 0; i < 4; ++i)
#pragma unroll
    for (int j = 0; j < 4; ++j) ctxacc[i][j] = f32x4{0.f, 0.f, 0.f, 0.f};

#pragma unroll
  for (int hh = 0; hh < 2; ++hh) {
    const int h = 2 * w + hh;
    // scores S = Q_h (64x32) * K_h^T  -> 4x4 tiles, single K=32 MFMA step
    f32x4 sacc[4][4];
#pragma unroll
    for (int i = 0; i < 4; ++i)
#pragma unroll
      for (int j = 0; j < 4; ++j) sacc[i][j] = f32x4{0.f, 0.f, 0.f, 0.f};
    {
      bf16x8 qf[4], kf[4];
#pragma unroll
      for (int mt = 0; mt < 4; ++mt)
        qf[mt] = *(const bf16x8*)&Qb[mt * 16 + lo][h * 32 + g * 8];
#pragma unroll
      for (int nt = 0; nt < 4; ++nt)
        kf[nt] = *(const bf16x8*)&Kb[nt * 16 + lo][h * 32 + g * 8];
#pragma unroll
      for (int mt = 0; mt < 4; ++mt)
#pragma unroll
        for (int nt = 0; nt < 4; ++nt)
          sacc[mt][nt] = __builtin_amdgcn_mfma_f32_16x16x32_bf16(qf[mt], kf[nt], sacc[mt][nt], 0, 0, 0);
    }
    // softmax over cols; row r = mt*16 + g*4 + j, this lane holds cols nt*16+lo
#pragma unroll
    for (int mt = 0; mt < 4; ++mt) {
#pragma unroll
      for (int nt = 0; nt < 4; ++nt) sacc[mt][nt] *= SCALE;
#pragma unroll
      for (int j = 0; j < 4; ++j) {
        float mx = fmaxf(fmaxf(sacc[mt][0][j], sacc[mt][1][j]),
                         fmaxf(sacc[mt][2][j], sacc[mt][3][j]));
#pragma unroll
        for (int off = 8; off > 0; off >>= 1) mx = fmaxf(mx, __shfl_xor(mx, off, 64));
        float e0 = __expf(sacc[mt][0][j] - mx);
        float e1 = __expf(sacc[mt][1][j] - mx);
        float e2 = __expf(sacc[mt][2][j] - mx);
        float e3 = __expf(sacc[mt][3][j] - mx);
        float s = e0 + e1 + e2 + e3;
#pragma unroll
        for (int off = 8; off > 0; off >>= 1) s += __shfl_xor(s, off, 64);
        float rinv = __builtin_amdgcn_rcpf(s);
        int r = mt * 16 + g * 4 + j;
        Pw[w][r][0 * 16 + lo] = f2bf(e0 * rinv);
        Pw[w][r][1 * 16 + lo] = f2bf(e1 * rinv);
        Pw[w][r][2 * 16 + lo] = f2bf(e2 * rinv);
        Pw[w][r][3 * 16 + lo] = f2bf(e3 * rinv);
      }
    }
    // ctx_h = P (64x64) * V_h (64x32): accumulate into ctxacc cols hh*2+vt
#pragma unroll
    for (int kk = 0; kk < 2; ++kk) {
      bf16x8 pf[4], vf[2];
#pragma unroll
      for (int mt = 0; mt < 4; ++mt)
        pf[mt] = *(const bf16x8*)&Pw[w][mt * 16 + lo][kk * 32 + g * 8];
#pragma unroll
      for (int vt = 0; vt < 2; ++vt)
        vf[vt] = *(const bf16x8*)&Vt[h * 32 + vt * 16 + lo][kk * 32 + g * 8];
#pragma unroll
      for (int mt = 0; mt < 4; ++mt)
#pragma unroll
        for (int vt = 0; vt < 2; ++vt)
          ctxacc[mt][hh * 2 + vt] = __builtin_amdgcn_mfma_f32_16x16x32_bf16(
              pf[mt], vf[vt], ctxacc[mt][hh * 2 + vt], 0, 0, 0);
    }
  }

  // ---- residual: ctxacc += X * W_res (same tile layout) ----
#pragma unroll
  for (int kk = 0; kk < 4; ++kk) {
    bf16x8 af[4], bw[4];
#pragma unroll
    for (int mt = 0; mt < 4; ++mt)
      af[mt] = *(const bf16x8*)&Xb[mt * 16 + lo][kk * 32 + g * 8];
#pragma unroll
    for (int nt = 0; nt < 4; ++nt)
      bw[nt] = *(const bf16x8*)(wsr + (c0 + nt * 16 + lo) * DIM + kk * 32 + g * 8);
#pragma unroll
    for (int mt = 0; mt < 4; ++mt)
#pragma unroll
      for (int nt = 0; nt < 4; ++nt)
        ctxacc[mt][nt] = __builtin_amdgcn_mfma_f32_16x16x32_bf16(af[mt], bw[nt], ctxacc[mt][nt], 0, 0, 0);
  }

  // ---- ReLU + store ----
  {
    float* ob = outg + (size_t)b * (SEQ * HKC);
#pragma unroll
    for (int mt = 0; mt < 4; ++mt)
#pragma unroll
      for (int ct = 0; ct < 4; ++ct) {
        int c = c0 + ct * 16 + lo;
#pragma unroll
        for (int j = 0; j < 4; ++j) {
          int m = mt * 16 + g * 4 + j;
          ob[m * HKC + c] = fmaxf(ctxacc[mt][ct][j], 0.f);
        }
      }
  }
}

extern "C" void kernel_launch(void* const* d_in, const int* in_sizes, int n_in,
                              void* d_out, int out_size, void* d_ws, size_t ws_size,
                              hipStream_t stream) {
  const float* x  = (const float*)d_in[0];
  const float* Wq = (const float*)d_in[1];
  const float* Wk = (const float*)d_in[2];
  const float* Wv = (const float*)d_in[3];
  const float* Wr = (const float*)d_in[4];
  bf16_t* ws = (bf16_t*)d_ws;
  float* out = (float*)d_out;

  prep_weights<<<512, 256, 0, stream>>>(Wq, Wk, Wv, Wr, ws);
  fused_attn<<<NB, 256, 0, stream>>>(x, ws, out);
}

// Round 3
// 252.044 us; speedup vs baseline: 1.2655x; 1.2655x over previous
//
#include <hip/hip_runtime.h>

#define NB    4096
#define SEQ   64
#define DIM   128
#define NHEAD 8
#define ATTD  32
#define HKC   256
#define SCALE 0.17677669529663687f

typedef __bf16 bf16_t;
typedef __bf16 bf16x8 __attribute__((ext_vector_type(8)));
typedef __bf16 bf16x4 __attribute__((ext_vector_type(4)));
typedef float  f32x4  __attribute__((ext_vector_type(4)));
typedef unsigned int u32;

static __device__ __forceinline__ bf16_t f2bf(float f) {
  unsigned u = __builtin_bit_cast(unsigned, f);
  u = (u + 0x7FFFu + ((u >> 16) & 1u)) >> 16;
  unsigned short s = (unsigned short)u;
  return __builtin_bit_cast(bf16_t, s);
}

// pack two f32 -> dword of 2 bf16 (lo=a, hi=b), RNE — pure bit math, no asm
static __device__ __forceinline__ u32 pkbf(float a, float b) {
  unsigned ua = __builtin_bit_cast(unsigned, a);
  ua = (ua + 0x7FFFu + ((ua >> 16) & 1u)) >> 16;
  unsigned ub = __builtin_bit_cast(unsigned, b);
  ub = (ub + 0x7FFFu + ((ub >> 16) & 1u)) & 0xFFFF0000u;
  return (ua & 0xFFFFu) | ub;
}

// D-layout -> MFMA A/B-frag merge, all-__shfl version.
// Input: two 16x16 D-tiles t0 (X rows 0-15), t1 (rows 16-31); lane (g,lo)
// reg j = value (X = 4g+j, lo). Output: bf16x8 frag, lane (g,lo) elem e =
// value (X = 8g+e, lo). lo-dim untouched.
// Derivation: output dword d holds X-pair (8g+2d, 8g+2d+1). X8=8g+2d < 16 ->
// from t0 (p-regs) else t1 (q-regs, Xr=X8-16); source group gs = Xr>>2 ->
// source lane = lo + 16*gs; dword-within-source = (Xr>>1)&1 = d&1.
// gs for d in {0,1}: 2*(g&1); for d in {2,3}: 2*(g&1)+1.
static __device__ __forceinline__ bf16x8 merge2(f32x4 t0, f32x4 t1, int lo, int g) {
  u32 p0 = pkbf(t0[0], t0[1]);
  u32 p1 = pkbf(t0[2], t0[3]);
  u32 q0 = pkbf(t1[0], t1[1]);
  u32 q1 = pkbf(t1[2], t1[3]);
  const int srcA = lo + ((g & 1) << 5);
  const int srcB = srcA + 16;
  u32 a0 = (u32)__shfl((int)p0, srcA, 64);
  u32 a1 = (u32)__shfl((int)p1, srcA, 64);
  u32 b0 = (u32)__shfl((int)p0, srcB, 64);
  u32 b1 = (u32)__shfl((int)p1, srcB, 64);
  u32 c0 = (u32)__shfl((int)q0, srcA, 64);
  u32 c1 = (u32)__shfl((int)q1, srcA, 64);
  u32 d0 = (u32)__shfl((int)q0, srcB, 64);
  u32 d1 = (u32)__shfl((int)q1, srcB, 64);
  const bool glow = (g < 2);
  union { u32 u[4]; bf16x8 v; } r;
  r.u[0] = glow ? a0 : c0;   // e=0,1 : X=8g+0,1
  r.u[1] = glow ? a1 : c1;   // e=2,3
  r.u[2] = glow ? b0 : d0;   // e=4,5
  r.u[3] = glow ? b1 : d1;   // e=6,7
  return r.v;
}

// ws layout (bf16): [0:32768) WqT[c][d] (pre-scaled by SCALE), [32768:65536) WkT,
// [65536:98304) WvT, [98304:131072) WresT; c = h*32+a (or res col), d = 0..127.
__global__ void prep_weights(const float* __restrict__ Wq,
                             const float* __restrict__ Wk,
                             const float* __restrict__ Wv,
                             const float* __restrict__ Wr,
                             bf16_t* __restrict__ ws) {
  int idx = blockIdx.x * 256 + threadIdx.x;  // 0..131071
  int m = idx >> 15;
  int e = idx & 32767;
  int c = e >> 7;
  int d = e & 127;
  float v;
  if (m == 0)      v = Wq[((c >> 5) * DIM + d) * ATTD + (c & 31)] * SCALE;
  else if (m == 1) v = Wk[((c >> 5) * DIM + d) * ATTD + (c & 31)];
  else if (m == 2) v = Wv[((c >> 5) * DIM + d) * ATTD + (c & 31)];
  else             v = Wr[d * HKC + c];
  ws[idx] = f2bf(v);
}

// One block per batch; 4 waves; wave w handles heads {2w,2w+1} = out cols [64w,64w+64).
// Only LDS: X tile. One barrier. Everything else in registers via merge2.
__launch_bounds__(256, 3)
__global__ void fused_attn(const float* __restrict__ xg,
                           const bf16_t* __restrict__ ws,
                           float* __restrict__ outg) {
  __shared__ bf16_t Xb[64][136];  // pad 8 -> row 272B, 2-way-max bank aliasing (free)

  const int t  = threadIdx.x;
  const int w  = t >> 6;
  const int l  = t & 63;
  const int lo = l & 15;
  const int g  = l >> 4;
  const int b  = blockIdx.x;

  { // stage X -> LDS (bf16)
    const float* xb = xg + (size_t)b * (SEQ * DIM);
#pragma unroll
    for (int i = 0; i < 8; ++i) {
      int idx = i * 1024 + t * 4;
      float4 v = *(const float4*)(xb + idx);
      bf16x4 p;
      p[0] = f2bf(v.x); p[1] = f2bf(v.y); p[2] = f2bf(v.z); p[3] = f2bf(v.w);
      *(bf16x4*)&Xb[idx >> 7][idx & 127] = p;
    }
  }
  __syncthreads();

  const bf16_t* wsq = ws;
  const bf16_t* wsk = ws + 32768;
  const bf16_t* wsv = ws + 65536;
  const bf16_t* wsr = ws + 98304;
  float* ob = outg + (size_t)b * (SEQ * HKC);
  const f32x4 z4 = {0.f, 0.f, 0.f, 0.f};

#pragma unroll
  for (int hh = 0; hh < 2; ++hh) {
    const int hc = w * 64 + hh * 32;  // weight col base == output col base

    // ---- Q^T = (SCALE*Wq)^T X^T : tiles [at][mt], rows a, cols m ----
    f32x4 accq[2][4];
#pragma unroll
    for (int i = 0; i < 2; ++i)
#pragma unroll
      for (int j = 0; j < 4; ++j) accq[i][j] = z4;
#pragma unroll
    for (int kk = 0; kk < 4; ++kk) {
      bf16x8 aw[2], bx[4];
#pragma unroll
      for (int at = 0; at < 2; ++at)
        aw[at] = *(const bf16x8*)(wsq + (hc + at * 16 + lo) * DIM + kk * 32 + g * 8);
#pragma unroll
      for (int mt = 0; mt < 4; ++mt)
        bx[mt] = *(const bf16x8*)&Xb[mt * 16 + lo][kk * 32 + g * 8];
#pragma unroll
      for (int at = 0; at < 2; ++at)
#pragma unroll
        for (int mt = 0; mt < 4; ++mt)
          accq[at][mt] = __builtin_amdgcn_mfma_f32_16x16x32_bf16(aw[at], bx[mt], accq[at][mt], 0, 0, 0);
    }
    bf16x8 qf[4];  // B-frags for S^T: col m = lo, k = a = 8g+e
#pragma unroll
    for (int mt = 0; mt < 4; ++mt) qf[mt] = merge2(accq[0][mt], accq[1][mt], lo, g);

    // ---- K^T = Wk^T X^T : tiles [at][nt] ----
    f32x4 acck[2][4];
#pragma unroll
    for (int i = 0; i < 2; ++i)
#pragma unroll
      for (int j = 0; j < 4; ++j) acck[i][j] = z4;
#pragma unroll
    for (int kk = 0; kk < 4; ++kk) {
      bf16x8 aw[2], bx[4];
#pragma unroll
      for (int at = 0; at < 2; ++at)
        aw[at] = *(const bf16x8*)(wsk + (hc + at * 16 + lo) * DIM + kk * 32 + g * 8);
#pragma unroll
      for (int nt = 0; nt < 4; ++nt)
        bx[nt] = *(const bf16x8*)&Xb[nt * 16 + lo][kk * 32 + g * 8];
#pragma unroll
      for (int at = 0; at < 2; ++at)
#pragma unroll
        for (int nt = 0; nt < 4; ++nt)
          acck[at][nt] = __builtin_amdgcn_mfma_f32_16x16x32_bf16(aw[at], bx[nt], acck[at][nt], 0, 0, 0);
    }
    bf16x8 kf[4];  // A-frags for S^T: row n = lo, k = a = 8g+e
#pragma unroll
    for (int nt = 0; nt < 4; ++nt) kf[nt] = merge2(acck[0][nt], acck[1][nt], lo, g);

    // ---- S^T = K Q^T (per mt), softmax over n, P -> A-frags ----
    bf16x8 pf[4][2];  // [mt][kk2]: row m = lo, k = n = kk2*32 + 8g+e
#pragma unroll
    for (int mt = 0; mt < 4; ++mt) {
      f32x4 sv[4];
#pragma unroll
      for (int nt = 0; nt < 4; ++nt)
        sv[nt] = __builtin_amdgcn_mfma_f32_16x16x32_bf16(kf[nt], qf[mt], z4, 0, 0, 0);
      float mx = sv[0][0];
#pragma unroll
      for (int nt = 0; nt < 4; ++nt)
#pragma unroll
        for (int j = 0; j < 4; ++j) mx = fmaxf(mx, sv[nt][j]);
      mx = fmaxf(mx, __shfl_xor(mx, 16, 64));
      mx = fmaxf(mx, __shfl_xor(mx, 32, 64));
      float sum = 0.f;
#pragma unroll
      for (int nt = 0; nt < 4; ++nt)
#pragma unroll
        for (int j = 0; j < 4; ++j) {
          float e = __expf(sv[nt][j] - mx);
          sv[nt][j] = e;
          sum += e;
        }
      sum += __shfl_xor(sum, 16, 64);
      sum += __shfl_xor(sum, 32, 64);
      float rinv = __builtin_amdgcn_rcpf(sum);
#pragma unroll
      for (int nt = 0; nt < 4; ++nt) sv[nt] *= rinv;
      pf[mt][0] = merge2(sv[0], sv[1], lo, g);
      pf[mt][1] = merge2(sv[2], sv[3], lo, g);
    }

    // ---- V = X Wv : tiles [mt][ct], rows n(seq), cols c ----
    f32x4 accv[4][2];
#pragma unroll
    for (int i = 0; i < 4; ++i)
#pragma unroll
      for (int j = 0; j < 2; ++j) accv[i][j] = z4;
#pragma unroll
    for (int kk = 0; kk < 4; ++kk) {
      bf16x8 ax[4], bw[2];
#pragma unroll
      for (int mt = 0; mt < 4; ++mt)
        ax[mt] = *(const bf16x8*)&Xb[mt * 16 + lo][kk * 32 + g * 8];
#pragma unroll
      for (int ct = 0; ct < 2; ++ct)
        bw[ct] = *(const bf16x8*)(wsv + (hc + ct * 16 + lo) * DIM + kk * 32 + g * 8);
#pragma unroll
      for (int mt = 0; mt < 4; ++mt)
#pragma unroll
        for (int ct = 0; ct < 2; ++ct)
          accv[mt][ct] = __builtin_amdgcn_mfma_f32_16x16x32_bf16(ax[mt], bw[ct], accv[mt][ct], 0, 0, 0);
    }
    bf16x8 vf[2][2];  // [ct][kk2]: B-frags, col c = lo, k = n
#pragma unroll
    for (int ct = 0; ct < 2; ++ct) {
      vf[ct][0] = merge2(accv[0][ct], accv[1][ct], lo, g);
      vf[ct][1] = merge2(accv[2][ct], accv[3][ct], lo, g);
    }

    // ---- ctx = P V ----
    f32x4 ch[4][2];
#pragma unroll
    for (int mt = 0; mt < 4; ++mt)
#pragma unroll
      for (int ct = 0; ct < 2; ++ct) {
        f32x4 a = __builtin_amdgcn_mfma_f32_16x16x32_bf16(pf[mt][0], vf[ct][0], z4, 0, 0, 0);
        ch[mt][ct] = __builtin_amdgcn_mfma_f32_16x16x32_bf16(pf[mt][1], vf[ct][1], a, 0, 0, 0);
      }

    // ---- ctx += X Wres (this head's 32 cols) ----
#pragma unroll
    for (int kk = 0; kk < 4; ++kk) {
      bf16x8 ax[4], bw[2];
#pragma unroll
      for (int mt = 0; mt < 4; ++mt)
        ax[mt] = *(const bf16x8*)&Xb[mt * 16 + lo][kk * 32 + g * 8];
#pragma unroll
      for (int ct = 0; ct < 2; ++ct)
        bw[ct] = *(const bf16x8*)(wsr + (hc + ct * 16 + lo) * DIM + kk * 32 + g * 8);
#pragma unroll
      for (int mt = 0; mt < 4; ++mt)
#pragma unroll
        for (int ct = 0; ct < 2; ++ct)
          ch[mt][ct] = __builtin_amdgcn_mfma_f32_16x16x32_bf16(ax[mt], bw[ct], ch[mt][ct], 0, 0, 0);
    }

    // ---- ReLU + store (cols hc..hc+31) ----
#pragma unroll
    for (int mt = 0; mt < 4; ++mt)
#pragma unroll
      for (int ct = 0; ct < 2; ++ct) {
        int c = hc + ct * 16 + lo;
#pragma unroll
        for (int j = 0; j < 4; ++j) {
          int m = mt * 16 + g * 4 + j;
          ob[m * HKC + c] = fmaxf(ch[mt][ct][j], 0.f);
        }
      }
  }
}

extern "C" void kernel_launch(void* const* d_in, const int* in_sizes, int n_in,
                              void* d_out, int out_size, void* d_ws, size_t ws_size,
                              hipStream_t stream) {
  const float* x  = (const float*)d_in[0];
  const float* Wq = (const float*)d_in[1];
  const float* Wk = (const float*)d_in[2];
  const float* Wv = (const float*)d_in[3];
  const float* Wr = (const float*)d_in[4];
  bf16_t* ws = (bf16_t*)d_ws;
  float* out = (float*)d_out;

  prep_weights<<<512, 256, 0, stream>>>(Wq, Wk, Wv, Wr, ws);
  fused_attn<<<NB, 256, 0, stream>>>(x, ws, out);
}